// Round 14
// baseline (696.481 us; speedup 1.0000x reference)
//
#include <hip/hip_runtime.h>
#include <math.h>

// Problem constants: B=4, H=8, L=512, HD=64, D=512, RHO=0.1
// Workspace (floats):
//   Q   : 1M   [BH][512][64]   (QKV base; later reused as Of [B][L][512])
//   Kt  : 1M
//   V   : 1M
//   S   : 8M   [BH][512][512]  (scores -> later J -> softmax'd in pv staging)
//   Am  : 8M   (adjacency sum via atomics; stays A -- Â built on the fly)
//   T   : 8M   (Â@S output)
//   R   : 16K  (row inv-sqrt degrees)  MX/INV: 16K each (row max / inv-sum)

typedef __attribute__((ext_vector_type(8))) short short8v;
typedef __attribute__((ext_vector_type(4))) float f32x4;
typedef _Float16 h2 __attribute__((ext_vector_type(2)));

// ---------------------------------------------------------------------------
// bf16 split helper: pack 8 fp32 -> hi/lo bf16x8 (truncation split)
// ---------------------------------------------------------------------------
__device__ __forceinline__ void split8(const float* v, unsigned* hi, unsigned* lo)
{
    #pragma unroll
    for (int q = 0; q < 4; ++q) {
        const unsigned b0 = __float_as_uint(v[2 * q])     & 0xFFFF0000u;
        const unsigned b1 = __float_as_uint(v[2 * q + 1]) & 0xFFFF0000u;
        const float d0 = v[2 * q]     - __uint_as_float(b0);
        const float d1 = v[2 * q + 1] - __uint_as_float(b1);
        hi[q] = (b0 >> 16) | b1;
        lo[q] = (__float_as_uint(d0) >> 16) | (__float_as_uint(d1) & 0xFFFF0000u);
    }
}

// ---------------------------------------------------------------------------
// Split-bf16 MFMA GEMM. 128x128 tile, 256 threads (4 waves 2x2), K-step 32.
// BT=0: C = A @ B; BT=1: C = A @ B^T. acc = Ahi*Bhi + Ahi*Blo + Alo*Bhi.
// FA=1: A-operand is A_hat built on the fly: (R[i]*R[k])*(A[i][k] + (i==k)).
// FB=1 (BT=1 only): B-operand is A_hat rows, same formula.
// ---------------------------------------------------------------------------
template<int BT, int FA, int FB>
__global__ __launch_bounds__(256)
void gemm_mfma(const float* __restrict__ Ap, const float* __restrict__ Bp,
               float* __restrict__ Cp, const float* __restrict__ Rv,
               int K, int lda, int ldb, int ldc,
               long sA, long sB, long sC, float scale)
{
    const float* __restrict__ A = Ap + (long)blockIdx.z * sA;
    const float* __restrict__ B = Bp + (long)blockIdx.z * sB;
    float* __restrict__ C = Cp + (long)blockIdx.z * sC;
    const float* __restrict__ Rb = (FA || FB) ? Rv + ((long)blockIdx.z << 9) : nullptr;
    const int m0 = blockIdx.y << 7, n0 = blockIdx.x << 7;

    __shared__ short Ah[128 * 32], Al[128 * 32], Bh[128 * 32], Bl[128 * 32];

    const int tid = threadIdx.x;
    const int lane = tid & 63, wv = tid >> 6;
    const int wr = wv >> 1, wc = wv & 1;

    f32x4 acc[4][4] = {};

    for (int k0 = 0; k0 < K; k0 += 32) {
        {
            const int row = tid >> 1;
            const int swz = (row & 3) ^ ((row >> 2) & 3);
            #pragma unroll
            for (int gg = 0; gg < 2; ++gg) {
                const int g = ((tid & 1) << 1) + gg;
                const float* src = A + (long)(m0 + row) * lda + k0 + (g << 3);
                float v[8];
                *(float4*)&v[0] = *(const float4*)src;
                *(float4*)&v[4] = *(const float4*)(src + 4);
                if (FA) {
                    const float ri = Rb[m0 + row];
                    float rk[8];
                    *(float4*)&rk[0] = *(const float4*)(Rb + k0 + (g << 3));
                    *(float4*)&rk[4] = *(const float4*)(Rb + k0 + (g << 3) + 4);
                    #pragma unroll
                    for (int e = 0; e < 8; ++e) {
                        const float dg = (k0 + (g << 3) + e == m0 + row) ? 1.0f : 0.0f;
                        v[e] = (ri * rk[e]) * (v[e] + dg);
                    }
                }
                unsigned hi[4], lo[4];
                split8(v, hi, lo);
                const int off = row * 32 + ((g ^ swz) << 3);
                *(uint4*)&Ah[off] = *(uint4*)hi;
                *(uint4*)&Al[off] = *(uint4*)lo;
            }
        }
        if (BT) {
            const int row = tid >> 1;
            const int swz = (row & 3) ^ ((row >> 2) & 3);
            #pragma unroll
            for (int gg = 0; gg < 2; ++gg) {
                const int g = ((tid & 1) << 1) + gg;
                const float* src = B + (long)(n0 + row) * ldb + k0 + (g << 3);
                float v[8];
                *(float4*)&v[0] = *(const float4*)src;
                *(float4*)&v[4] = *(const float4*)(src + 4);
                if (FB) {
                    const float rn = Rb[n0 + row];
                    float rj[8];
                    *(float4*)&rj[0] = *(const float4*)(Rb + k0 + (g << 3));
                    *(float4*)&rj[4] = *(const float4*)(Rb + k0 + (g << 3) + 4);
                    #pragma unroll
                    for (int e = 0; e < 8; ++e) {
                        const float dg = (k0 + (g << 3) + e == n0 + row) ? 1.0f : 0.0f;
                        v[e] = (rn * rj[e]) * (v[e] + dg);
                    }
                }
                unsigned hi[4], lo[4];
                split8(v, hi, lo);
                const int off = row * 32 + ((g ^ swz) << 3);
                *(uint4*)&Bh[off] = *(uint4*)hi;
                *(uint4*)&Bl[off] = *(uint4*)lo;
            }
        } else {
            const int n = tid & 127;
            const int swz = (n & 3) ^ ((n >> 2) & 3);
            #pragma unroll
            for (int gg = 0; gg < 2; ++gg) {
                const int g = ((tid >> 7) << 1) + gg;
                float v[8];
                #pragma unroll
                for (int e = 0; e < 8; ++e)
                    v[e] = B[(long)(k0 + (g << 3) + e) * ldb + n0 + n];
                unsigned hi[4], lo[4];
                split8(v, hi, lo);
                const int off = n * 32 + ((g ^ swz) << 3);
                *(uint4*)&Bh[off] = *(uint4*)hi;
                *(uint4*)&Bl[off] = *(uint4*)lo;
            }
        }
        __syncthreads();

        {
            const int r = lane & 15, g = lane >> 4;
            const int lswz = (r & 3) ^ ((r >> 2) & 3);
            const int gslot = ((g ^ lswz) << 3);
            const int abase = ((wr << 6) + r) * 32 + gslot;
            const int bbase = ((wc << 6) + r) * 32 + gslot;
            short8v afh[4], afl[4], bfh[4], bfl[4];
            #pragma unroll
            for (int f = 0; f < 4; ++f) {
                afh[f] = *(short8v*)&Ah[abase + f * 512];
                afl[f] = *(short8v*)&Al[abase + f * 512];
                bfh[f] = *(short8v*)&Bh[bbase + f * 512];
                bfl[f] = *(short8v*)&Bl[bbase + f * 512];
            }
            #pragma unroll
            for (int fi = 0; fi < 4; ++fi)
                #pragma unroll
                for (int fj = 0; fj < 4; ++fj) {
                    acc[fi][fj] = __builtin_amdgcn_mfma_f32_16x16x32_bf16(
                        afh[fi], bfh[fj], acc[fi][fj], 0, 0, 0);
                    acc[fi][fj] = __builtin_amdgcn_mfma_f32_16x16x32_bf16(
                        afh[fi], bfl[fj], acc[fi][fj], 0, 0, 0);
                    acc[fi][fj] = __builtin_amdgcn_mfma_f32_16x16x32_bf16(
                        afl[fi], bfh[fj], acc[fi][fj], 0, 0, 0);
                }
        }
        __syncthreads();
    }

    // C/D layout: col = lane&15, row = (lane>>4)*4 + reg  [m89/m91]
    const int r = lane & 15, g = lane >> 4;
    #pragma unroll
    for (int fi = 0; fi < 4; ++fi) {
        const int gr0 = m0 + (wr << 6) + fi * 16 + g * 4;
        #pragma unroll
        for (int fj = 0; fj < 4; ++fj) {
            const int gc = n0 + (wc << 6) + fj * 16 + r;
            #pragma unroll
            for (int qq = 0; qq < 4; ++qq)
                C[(long)(gr0 + qq) * ldc + gc] = acc[fi][fj][qq] * scale;
        }
    }
}

// ---------------------------------------------------------------------------
// Fused QKV projection via split-bf16 MFMA: x[2048x512] @ {Wq|Wk|Wv}[512x512]
// -> QKV [3][BH][512][64]. Grid (12, 16).
// ---------------------------------------------------------------------------
__global__ __launch_bounds__(256)
void gemm_qkv_mfma(const float* __restrict__ x, const float* __restrict__ Wq,
                   const float* __restrict__ Wk, const float* __restrict__ Wv,
                   float* __restrict__ QKV)
{
    const int m0 = blockIdx.y << 7;
    const int ng = blockIdx.x << 7;
    const float* __restrict__ W = (ng < 512) ? Wq : (ng < 1024) ? Wk : Wv;
    const int n0 = ng & 511;
    float* __restrict__ C = QKV + (long)(ng >> 9) * (1 << 20);

    __shared__ short Ah[128 * 32], Al[128 * 32], Bh[128 * 32], Bl[128 * 32];

    const int tid = threadIdx.x;
    const int lane = tid & 63, wv = tid >> 6;
    const int wr = wv >> 1, wc = wv & 1;

    f32x4 acc[4][4] = {};

    for (int k0 = 0; k0 < 512; k0 += 32) {
        {
            const int row = tid >> 1;
            const int swz = (row & 3) ^ ((row >> 2) & 3);
            #pragma unroll
            for (int gg = 0; gg < 2; ++gg) {
                const int g = ((tid & 1) << 1) + gg;
                const float* src = x + (long)(m0 + row) * 512 + k0 + (g << 3);
                float v[8];
                *(float4*)&v[0] = *(const float4*)src;
                *(float4*)&v[4] = *(const float4*)(src + 4);
                unsigned hi[4], lo[4];
                split8(v, hi, lo);
                const int off = row * 32 + ((g ^ swz) << 3);
                *(uint4*)&Ah[off] = *(uint4*)hi;
                *(uint4*)&Al[off] = *(uint4*)lo;
            }
        }
        {
            const int n = tid & 127;
            const int swz = (n & 3) ^ ((n >> 2) & 3);
            #pragma unroll
            for (int gg = 0; gg < 2; ++gg) {
                const int g = ((tid >> 7) << 1) + gg;
                float v[8];
                #pragma unroll
                for (int e = 0; e < 8; ++e)
                    v[e] = W[(long)(k0 + (g << 3) + e) * 512 + n0 + n];
                unsigned hi[4], lo[4];
                split8(v, hi, lo);
                const int off = n * 32 + ((g ^ swz) << 3);
                *(uint4*)&Bh[off] = *(uint4*)hi;
                *(uint4*)&Bl[off] = *(uint4*)lo;
            }
        }
        __syncthreads();

        {
            const int r = lane & 15, g = lane >> 4;
            const int lswz = (r & 3) ^ ((r >> 2) & 3);
            const int gslot = ((g ^ lswz) << 3);
            const int abase = ((wr << 6) + r) * 32 + gslot;
            const int bbase = ((wc << 6) + r) * 32 + gslot;
            short8v afh[4], afl[4], bfh[4], bfl[4];
            #pragma unroll
            for (int f = 0; f < 4; ++f) {
                afh[f] = *(short8v*)&Ah[abase + f * 512];
                afl[f] = *(short8v*)&Al[abase + f * 512];
                bfh[f] = *(short8v*)&Bh[bbase + f * 512];
                bfl[f] = *(short8v*)&Bl[bbase + f * 512];
            }
            #pragma unroll
            for (int fi = 0; fi < 4; ++fi)
                #pragma unroll
                for (int fj = 0; fj < 4; ++fj) {
                    acc[fi][fj] = __builtin_amdgcn_mfma_f32_16x16x32_bf16(
                        afh[fi], bfh[fj], acc[fi][fj], 0, 0, 0);
                    acc[fi][fj] = __builtin_amdgcn_mfma_f32_16x16x32_bf16(
                        afh[fi], bfl[fj], acc[fi][fj], 0, 0, 0);
                    acc[fi][fj] = __builtin_amdgcn_mfma_f32_16x16x32_bf16(
                        afl[fi], bfh[fj], acc[fi][fj], 0, 0, 0);
                }
        }
        __syncthreads();
    }

    const int r = lane & 15, g = lane >> 4;
    #pragma unroll
    for (int fi = 0; fi < 4; ++fi) {
        const int gr0 = m0 + (wr << 6) + fi * 16 + g * 4;
        #pragma unroll
        for (int fj = 0; fj < 4; ++fj) {
            const int nl = n0 + (wc << 6) + fj * 16 + r;
            const int h = nl >> 6, d = nl & 63;
            #pragma unroll
            for (int qq = 0; qq < 4; ++qq) {
                const int m = gr0 + qq;
                const int b = m >> 9, l = m & 511;
                C[((long)((b * 8 + h) * 512 + l)) * 64 + d] = acc[fi][fj][qq];
            }
        }
    }
}

// ---------------------------------------------------------------------------
// Adjacency v11: packed-fp16 inner loop + register prefetch + j-split x2,
// partials accumulated into A via atomicAdd (exactly 2 adds/address, fp add
// of two values is commutative -> bit-deterministic). A must be zeroed first.
//   contribution = 2^-15 * sum_{j in half} u·[u > 6.4], u = S_ij*S_kj, diag 0.
// Per j-PAIR: d = pk_fma(a,b,-6.4); t = pk_max(d,0);
//   m = pk_min(pk_fma(t,32768,t), pk_add(t,6.4)); acc = pk_add(m, acc).
// ---------------------------------------------------------------------------
__global__ __launch_bounds__(256, 4)
void adj_kernel(const float* __restrict__ S, float* __restrict__ A)
{
    const int bh = blockIdx.z;
    const float* __restrict__ Sh = S + (long)bh * 262144;
    float* __restrict__ Ph = A + (long)bh * 262144;
    const int jbase = blockIdx.y << 8;

    int ti = 0, rem = blockIdx.x;
    while (rem >= 8 - ti) { rem -= 8 - ti; ++ti; }
    const int tk = ti + rem;
    const int i0 = ti << 6, k0 = tk << 6;

    __shared__ __align__(16) char smem_raw[17408];

    const int tid  = threadIdx.x;
    const int lane = tid & 63;
    const int wv   = tid >> 6;
    const int ly8  = (lane >> 3) << 3;
    const int lx8  = (lane & 7) << 3;
    const int r4   = lane >> 2;
    const int q    = lane & 3;

    unsigned (*stgL)[68] = (unsigned(*)[68])(smem_raw + wv * 4352);
    unsigned (*stgR)[68] = (unsigned(*)[68])(smem_raw + wv * 4352 + 2176);

    const unsigned nC  = 0xC666C666u;    // (-6.4, -6.4) f16
    const unsigned zz  = 0x00000000u;
    const unsigned big = 0x78007800u;    // (32768, 32768)
    const unsigned cc  = 0x46664666u;    // (6.4, 6.4)

    unsigned acc2[8][8] = {};

    const int jw = jbase + (wv << 6);
    const float* srcL = Sh + (long)(i0 + r4) * 512 + jw + (q << 2);
    const float* srcR = Sh + (long)(k0 + r4) * 512 + jw + (q << 2);

    float4 rl[4], rr[4];
    #pragma unroll
    for (int p = 0; p < 4; ++p) {
        rl[p] = *(const float4*)(srcL + (long)(p << 4) * 512);
        rr[p] = *(const float4*)(srcR + (long)(p << 4) * 512);
    }

    for (int c = 0; c < 4; ++c) {
        #pragma unroll
        for (int p = 0; p < 4; ++p) {
            const int row = r4 + (p << 4);
            h2 h0, h1;
            h0[0] = (_Float16)rl[p].x; h0[1] = (_Float16)rl[p].y;
            h1[0] = (_Float16)rl[p].z; h1[1] = (_Float16)rl[p].w;
            stgL[(q << 1) + 0][row] = __builtin_bit_cast(unsigned, h0);
            stgL[(q << 1) + 1][row] = __builtin_bit_cast(unsigned, h1);
            h0[0] = (_Float16)rr[p].x; h0[1] = (_Float16)rr[p].y;
            h1[0] = (_Float16)rr[p].z; h1[1] = (_Float16)rr[p].w;
            stgR[(q << 1) + 0][row] = __builtin_bit_cast(unsigned, h0);
            stgR[(q << 1) + 1][row] = __builtin_bit_cast(unsigned, h1);
        }
        if (c < 3) {
            const int joff = (c + 1) << 4;
            #pragma unroll
            for (int p = 0; p < 4; ++p) {
                rl[p] = *(const float4*)(srcL + (long)(p << 4) * 512 + joff);
                rr[p] = *(const float4*)(srcR + (long)(p << 4) * 512 + joff);
            }
        }
        asm volatile("s_waitcnt lgkmcnt(0)" ::: "memory");
        __builtin_amdgcn_sched_barrier(0);
        #pragma unroll
        for (int jp = 0; jp < 8; ++jp) {
            unsigned a2[8], b2[8];
            *(uint4*)&a2[0] = *(const uint4*)&stgL[jp][ly8];
            *(uint4*)&a2[4] = *(const uint4*)&stgL[jp][ly8 + 4];
            *(uint4*)&b2[0] = *(const uint4*)&stgR[jp][lx8];
            *(uint4*)&b2[4] = *(const uint4*)&stgR[jp][lx8 + 4];
            #pragma unroll
            for (int i = 0; i < 8; ++i)
                #pragma unroll
                for (int j = 0; j < 8; ++j) {
                    unsigned d, t, m1, m2, m;
                    asm("v_pk_fma_f16 %0, %1, %2, %3"
                        : "=v"(d) : "v"(a2[i]), "v"(b2[j]), "v"(nC));
                    asm("v_pk_max_f16 %0, %1, %2"
                        : "=v"(t) : "v"(d), "v"(zz));
                    asm("v_pk_fma_f16 %0, %1, %2, %3"
                        : "=v"(m1) : "v"(t), "v"(big), "v"(t));
                    asm("v_pk_add_f16 %0, %1, %2"
                        : "=v"(m2) : "v"(t), "v"(cc));
                    asm("v_pk_min_f16 %0, %1, %2"
                        : "=v"(m) : "v"(m1), "v"(m2));
                    asm("v_pk_add_f16 %0, %1, %0"
                        : "+v"(acc2[i][j]) : "v"(m));
                }
        }
    }

    // ---- quarter-wise fp32 reduce: (w0+w1)+(w3+w2) -> wave 0 ----
    float* buf0 = (float*)smem_raw;
    float* buf1 = (float*)(smem_raw + 4352);
    float  f[8][8];

    #pragma unroll
    for (int qp = 0; qp < 4; ++qp) {
        float v[16];
        #pragma unroll
        for (int e = 0; e < 16; ++e) {
            const h2 hh = __builtin_bit_cast(h2, acc2[(qp << 1) + (e >> 3)][e & 7]);
            v[e] = (float)hh[0] + (float)hh[1];
        }
        __syncthreads();
        if (wv == 1 || wv == 2) {
            float* dst = (wv == 1 ? buf0 : buf1) + lane * 17;
            #pragma unroll
            for (int e = 0; e < 16; ++e) dst[e] = v[e];
        }
        __syncthreads();
        if (wv == 0 || wv == 3) {
            const float* src = (wv == 0 ? buf0 : buf1) + lane * 17;
            #pragma unroll
            for (int e = 0; e < 16; ++e) v[e] += src[e];
        }
        __syncthreads();
        if (wv == 3) {
            float* dst = buf0 + lane * 17;
            #pragma unroll
            for (int e = 0; e < 16; ++e) dst[e] = v[e];
        }
        __syncthreads();
        if (wv == 0) {
            const float* src = buf0 + lane * 17;
            #pragma unroll
            for (int e = 0; e < 16; ++e)
                f[(qp << 1) + (e >> 3)][e & 7] = v[e] + src[e];
        }
    }

    if (wv == 0) {
        const float SC = 1.0f / 32768.0f;    // 2^-15 exact
        #pragma unroll
        for (int i = 0; i < 8; ++i)
            #pragma unroll
            for (int j = 0; j < 8; ++j)
                f[i][j] *= SC;
        if (ti == tk) {
            #pragma unroll
            for (int i = 0; i < 8; ++i)
                #pragma unroll
                for (int j = 0; j < 8; ++j)
                    if (ly8 + i == lx8 + j) f[i][j] = 0.0f;
        }
        #pragma unroll
        for (int i = 0; i < 8; ++i)
            #pragma unroll
            for (int j = 0; j < 8; ++j)
                atomicAdd(Ph + (long)(i0 + ly8 + i) * 512 + k0 + lx8 + j, f[i][j]);
        if (ti != tk) {
            #pragma unroll
            for (int j = 0; j < 8; ++j)
                #pragma unroll
                for (int i = 0; i < 8; ++i)
                    atomicAdd(Ph + (long)(k0 + lx8 + j) * 512 + i0 + ly8 + i, f[i][j]);
        }
    }
}

// ---------------------------------------------------------------------------
// Row degree: R[row] = 1/sqrt(clip(1 + sum_k A[row,k], 1e-6))
// ---------------------------------------------------------------------------
__global__ __launch_bounds__(256)
void rowsum_kernel(const float* __restrict__ A, float* __restrict__ R)
{
    const int row = (blockIdx.x << 2) + (threadIdx.x >> 6);
    const int lane = threadIdx.x & 63;
    const float* p = A + (long)row * 512;
    float s = 0.0f;
    #pragma unroll
    for (int t = 0; t < 8; ++t) s += p[lane + (t << 6)];
    #pragma unroll
    for (int off = 32; off; off >>= 1) s += __shfl_xor(s, off, 64);
    if (lane == 0) R[row] = 1.0f / sqrtf(fmaxf(1.0f + s, 1e-6f));
}

// ---------------------------------------------------------------------------
// Row max + inverse exp-sum for softmax. Wave per row, 4 rows/block.
// Identical reduce order to the previous softmax kernel (bit-identical).
// ---------------------------------------------------------------------------
__global__ __launch_bounds__(256)
void rowmaxsum_kernel(const float* __restrict__ J, float* __restrict__ MX,
                      float* __restrict__ INV)
{
    const int row = (blockIdx.x << 2) + (threadIdx.x >> 6);
    const int lane = threadIdx.x & 63;
    const float* p = J + (long)row * 512 + (lane << 3);
    float4 v0 = *(const float4*)p;
    float4 v1 = *(const float4*)(p + 4);
    float mx = fmaxf(fmaxf(fmaxf(v0.x, v0.y), fmaxf(v0.z, v0.w)),
                     fmaxf(fmaxf(v1.x, v1.y), fmaxf(v1.z, v1.w)));
    #pragma unroll
    for (int off = 32; off; off >>= 1) mx = fmaxf(mx, __shfl_xor(mx, off, 64));
    float e[8];
    e[0] = __expf(v0.x - mx); e[1] = __expf(v0.y - mx);
    e[2] = __expf(v0.z - mx); e[3] = __expf(v0.w - mx);
    e[4] = __expf(v1.x - mx); e[5] = __expf(v1.y - mx);
    e[6] = __expf(v1.z - mx); e[7] = __expf(v1.w - mx);
    float s = (((e[0] + e[1]) + (e[2] + e[3])) + ((e[4] + e[5]) + (e[6] + e[7])));
    #pragma unroll
    for (int off = 32; off; off >>= 1) s += __shfl_xor(s, off, 64);
    if (lane == 0) { MX[row] = mx; INV[row] = 1.0f / s; }
}

// ---------------------------------------------------------------------------
// O = softmax(J) @ V per head via split-bf16 MFMA, softmax applied in staging
// (p = expf(J - MX[row]) * INV[row] -- identical arithmetic to the old
// standalone softmax kernel). Writes DIRECTLY to Of [B][L][H*HD].
// 128x64 tile, 4 waves stacked on M. Grid (1, 4, 32).
// ---------------------------------------------------------------------------
__global__ __launch_bounds__(256)
void gemm_pv_mfma(const float* __restrict__ J, const float* __restrict__ V,
                  const float* __restrict__ MX, const float* __restrict__ INV,
                  float* __restrict__ Of)
{
    const int bh = blockIdx.z;
    const float* __restrict__ Pp = J + (long)bh * 262144;
    const float* __restrict__ Vp = V + (long)bh * 32768;
    const float* __restrict__ MXb = MX + ((long)bh << 9);
    const float* __restrict__ INVb = INV + ((long)bh << 9);
    const int bb = bh >> 3, hh = bh & 7;
    const int m0 = blockIdx.y << 7;

    __shared__ short Ph[128 * 32], Pl[128 * 32], Vh[64 * 32], Vl[64 * 32];

    const int tid = threadIdx.x;
    const int lane = tid & 63, wv = tid >> 6;

    f32x4 acc[2][4] = {};

    for (int k0 = 0; k0 < 512; k0 += 32) {
        {
            const int row = tid >> 1;
            const float mx = MXb[m0 + row], inv = INVb[m0 + row];
            const int swz = (row & 3) ^ ((row >> 2) & 3);
            #pragma unroll
            for (int gg = 0; gg < 2; ++gg) {
                const int g = ((tid & 1) << 1) + gg;
                const float* src = Pp + (long)(m0 + row) * 512 + k0 + (g << 3);
                float v[8];
                *(float4*)&v[0] = *(const float4*)src;
                *(float4*)&v[4] = *(const float4*)(src + 4);
                #pragma unroll
                for (int e = 0; e < 8; ++e)
                    v[e] = __expf(v[e] - mx) * inv;
                unsigned hi[4], lo[4];
                split8(v, hi, lo);
                const int off = row * 32 + ((g ^ swz) << 3);
                *(uint4*)&Ph[off] = *(uint4*)hi;
                *(uint4*)&Pl[off] = *(uint4*)lo;
            }
        }
        {
            const int n = tid & 63, g = tid >> 6;
            const int swz = (n & 3) ^ ((n >> 2) & 3);
            float v[8];
            #pragma unroll
            for (int e = 0; e < 8; ++e)
                v[e] = Vp[(long)(k0 + (g << 3) + e) * 64 + n];
            unsigned hi[4], lo[4];
            split8(v, hi, lo);
            const int off = n * 32 + ((g ^ swz) << 3);
            *(uint4*)&Vh[off] = *(uint4*)hi;
            *(uint4*)&Vl[off] = *(uint4*)lo;
        }
        __syncthreads();

        {
            const int r = lane & 15, g = lane >> 4;
            const int lswz = (r & 3) ^ ((r >> 2) & 3);
            const int gslot = ((g ^ lswz) << 3);
            short8v afh[2], afl[2], bfh[4], bfl[4];
            #pragma unroll
            for (int fi = 0; fi < 2; ++fi) {
                const int abase = ((wv << 5) + (fi << 4) + r) * 32 + gslot;
                afh[fi] = *(short8v*)&Ph[abase];
                afl[fi] = *(short8v*)&Pl[abase];
            }
            #pragma unroll
            for (int fj = 0; fj < 4; ++fj) {
                const int bbase = ((fj << 4) + r) * 32 + gslot;
                bfh[fj] = *(short8v*)&Vh[bbase];
                bfl[fj] = *(short8v*)&Vl[bbase];
            }
            #pragma unroll
            for (int fi = 0; fi < 2; ++fi)
                #pragma unroll
                for (int fj = 0; fj < 4; ++fj) {
                    acc[fi][fj] = __builtin_amdgcn_mfma_f32_16x16x32_bf16(
                        afh[fi], bfh[fj], acc[fi][fj], 0, 0, 0);
                    acc[fi][fj] = __builtin_amdgcn_mfma_f32_16x16x32_bf16(
                        afh[fi], bfl[fj], acc[fi][fj], 0, 0, 0);
                    acc[fi][fj] = __builtin_amdgcn_mfma_f32_16x16x32_bf16(
                        afl[fi], bfh[fj], acc[fi][fj], 0, 0, 0);
                }
        }
        __syncthreads();
    }

    const int r = lane & 15, g = lane >> 4;
    #pragma unroll
    for (int fi = 0; fi < 2; ++fi) {
        const int l0 = m0 + (wv << 5) + fi * 16 + g * 4;
        #pragma unroll
        for (int fj = 0; fj < 4; ++fj) {
            const int d = fj * 16 + r;
            #pragma unroll
            for (int qq = 0; qq < 4; ++qq)
                Of[((long)((bb << 9) + l0 + qq) << 9) + (hh << 6) + d] = acc[fi][fj][qq];
        }
    }
}

// ---------------------------------------------------------------------------
extern "C" void kernel_launch(void* const* d_in, const int* in_sizes, int n_in,
                              void* d_out, int out_size, void* d_ws, size_t ws_size,
                              hipStream_t stream)
{
    const float* x  = (const float*)d_in[0];
    const float* Wq = (const float*)d_in[1];
    const float* Wk = (const float*)d_in[2];
    const float* Wv = (const float*)d_in[3];
    const float* Wo = (const float*)d_in[4];
    float* out = (float*)d_out;

    float* ws = (float*)d_ws;
    float* Q  = ws;                       // 1M floats (QKV base; later Of)
    float* Kt = Q  + (1u << 20);          // 1M
    float* V  = Kt + (1u << 20);          // 1M
    float* S  = V  + (1u << 20);          // 8M
    float* Am = S  + (8u << 20);          // 8M (adjacency sum; zeroed each call)
    float* T  = Am + (8u << 20);          // 8M (Â@S output)
    float* R  = T  + (8u << 20);          // 16K
    float* MX = R  + 16384;               // 16K
    float* INV = MX + 16384;              // 16K

    dim3 blk(256);

    // 0) zero the adjacency accumulator (atomics add into it)
    hipMemsetAsync(Am, 0, (size_t)(8u << 20) * sizeof(float), stream);

    // 1) fused QKV projections (split-bf16 MFMA)
    gemm_qkv_mfma<<<dim3(12, 16, 1), blk, 0, stream>>>(x, Wq, Wk, Wv, Q);

    // 2) S = Q K^T per head (MFMA, K=64)
    gemm_mfma<1, 0, 0><<<dim3(4, 4, 32), blk, 0, stream>>>(Q, Kt, S, nullptr,
                                                           64, 64, 64, 512,
                                                           32768, 32768, 262144, 1.0f);

    // 3) adjacency (packed-fp16, j-split x2, atomicAdd into Am)
    adj_kernel<<<dim3(36, 2, 32), blk, 0, stream>>>(S, Am);

    // 4) row degrees -> R
    rowsum_kernel<<<dim3(4096), blk, 0, stream>>>(Am, R);

    // 5) T = Â @ S (Â built on the fly from Am + R during A-staging)
    gemm_mfma<0, 1, 0><<<dim3(4, 4, 32), blk, 0, stream>>>(Am, S, T, R,
                                                           512, 512, 512, 512,
                                                           262144, 262144, 262144, 1.0f);

    // 6) J = T @ Â^T / 8 -> S (Â built on the fly during B-staging)
    gemm_mfma<1, 0, 1><<<dim3(4, 4, 32), blk, 0, stream>>>(T, Am, S, R,
                                                           512, 512, 512, 512,
                                                           262144, 262144, 262144, 0.125f);

    // 7) row max + inv exp-sum of J
    rowmaxsum_kernel<<<dim3(4096), blk, 0, stream>>>(S, MX, INV);

    // 8) O = softmax(J) @ V -> Of directly (softmax in staging; reuse Q)
    gemm_pv_mfma<<<dim3(1, 4, 32), blk, 0, stream>>>(S, V, MX, INV, Q);

    // 9) out = Of @ Wo (MFMA)
    gemm_mfma<0, 0, 0><<<dim3(4, 16, 1), blk, 0, stream>>>(Q, Wo, out, nullptr,
                                                           512, 512, 512, 512,
                                                           0, 0, 0, 1.0f);
}

// Round 15
// 412.315 us; speedup vs baseline: 1.6892x; 1.6892x over previous
//
#include <hip/hip_runtime.h>
#include <math.h>

// Problem constants: B=4, H=8, L=512, HD=64, D=512, RHO=0.1
// Workspace (floats):
//   Q   : 1M   [BH][512][64]   (QKV base; later reused as Of [B][L][512])
//   Kt  : 1M
//   V   : 1M
//   S   : 8M   [BH][512][512]  (scores -> J -> softmax'd in pv staging)
//   Am  : 8M   (adj partial 0 -> A_hat in place)
//   T   : 8M   (adj partial 1 -> A_hat@S temp)
//   R   : 16K  (row inv-sqrt degrees); MX/INV: 16K each

typedef __attribute__((ext_vector_type(8))) short short8v;
typedef __attribute__((ext_vector_type(4))) float f32x4;
typedef _Float16 h2 __attribute__((ext_vector_type(2)));

// ---------------------------------------------------------------------------
// bf16 split helper: pack 8 fp32 -> hi/lo bf16x8 (truncation split)
// ---------------------------------------------------------------------------
__device__ __forceinline__ void split8(const float* v, unsigned* hi, unsigned* lo)
{
    #pragma unroll
    for (int q = 0; q < 4; ++q) {
        const unsigned b0 = __float_as_uint(v[2 * q])     & 0xFFFF0000u;
        const unsigned b1 = __float_as_uint(v[2 * q + 1]) & 0xFFFF0000u;
        const float d0 = v[2 * q]     - __uint_as_float(b0);
        const float d1 = v[2 * q + 1] - __uint_as_float(b1);
        hi[q] = (b0 >> 16) | b1;
        lo[q] = (__float_as_uint(d0) >> 16) | (__float_as_uint(d1) & 0xFFFF0000u);
    }
}

// ---------------------------------------------------------------------------
// Split-bf16 MFMA GEMM. 128x128 tile, 256 threads (4 waves 2x2), K-step 32.
// BT=0: C = A @ B; BT=1: C = A @ B^T. acc = Ahi*Bhi + Ahi*Blo + Alo*Bhi.
// ---------------------------------------------------------------------------
template<int BT>
__global__ __launch_bounds__(256)
void gemm_mfma(const float* __restrict__ Ap, const float* __restrict__ Bp,
               float* __restrict__ Cp, int K, int lda, int ldb, int ldc,
               long sA, long sB, long sC, float scale)
{
    const float* __restrict__ A = Ap + (long)blockIdx.z * sA;
    const float* __restrict__ B = Bp + (long)blockIdx.z * sB;
    float* __restrict__ C = Cp + (long)blockIdx.z * sC;
    const int m0 = blockIdx.y << 7, n0 = blockIdx.x << 7;

    __shared__ short Ah[128 * 32], Al[128 * 32], Bh[128 * 32], Bl[128 * 32];

    const int tid = threadIdx.x;
    const int lane = tid & 63, wv = tid >> 6;
    const int wr = wv >> 1, wc = wv & 1;

    f32x4 acc[4][4] = {};

    for (int k0 = 0; k0 < K; k0 += 32) {
        {
            const int row = tid >> 1;
            const int swz = (row & 3) ^ ((row >> 2) & 3);
            #pragma unroll
            for (int gg = 0; gg < 2; ++gg) {
                const int g = ((tid & 1) << 1) + gg;
                const float* src = A + (long)(m0 + row) * lda + k0 + (g << 3);
                float v[8];
                *(float4*)&v[0] = *(const float4*)src;
                *(float4*)&v[4] = *(const float4*)(src + 4);
                unsigned hi[4], lo[4];
                split8(v, hi, lo);
                const int off = row * 32 + ((g ^ swz) << 3);
                *(uint4*)&Ah[off] = *(uint4*)hi;
                *(uint4*)&Al[off] = *(uint4*)lo;
            }
        }
        if (BT) {
            const int row = tid >> 1;
            const int swz = (row & 3) ^ ((row >> 2) & 3);
            #pragma unroll
            for (int gg = 0; gg < 2; ++gg) {
                const int g = ((tid & 1) << 1) + gg;
                const float* src = B + (long)(n0 + row) * ldb + k0 + (g << 3);
                float v[8];
                *(float4*)&v[0] = *(const float4*)src;
                *(float4*)&v[4] = *(const float4*)(src + 4);
                unsigned hi[4], lo[4];
                split8(v, hi, lo);
                const int off = row * 32 + ((g ^ swz) << 3);
                *(uint4*)&Bh[off] = *(uint4*)hi;
                *(uint4*)&Bl[off] = *(uint4*)lo;
            }
        } else {
            const int n = tid & 127;
            const int swz = (n & 3) ^ ((n >> 2) & 3);
            #pragma unroll
            for (int gg = 0; gg < 2; ++gg) {
                const int g = ((tid >> 7) << 1) + gg;
                float v[8];
                #pragma unroll
                for (int e = 0; e < 8; ++e)
                    v[e] = B[(long)(k0 + (g << 3) + e) * ldb + n0 + n];
                unsigned hi[4], lo[4];
                split8(v, hi, lo);
                const int off = n * 32 + ((g ^ swz) << 3);
                *(uint4*)&Bh[off] = *(uint4*)hi;
                *(uint4*)&Bl[off] = *(uint4*)lo;
            }
        }
        __syncthreads();

        {
            const int r = lane & 15, g = lane >> 4;
            const int lswz = (r & 3) ^ ((r >> 2) & 3);
            const int gslot = ((g ^ lswz) << 3);
            const int abase = ((wr << 6) + r) * 32 + gslot;
            const int bbase = ((wc << 6) + r) * 32 + gslot;
            short8v afh[4], afl[4], bfh[4], bfl[4];
            #pragma unroll
            for (int f = 0; f < 4; ++f) {
                afh[f] = *(short8v*)&Ah[abase + f * 512];
                afl[f] = *(short8v*)&Al[abase + f * 512];
                bfh[f] = *(short8v*)&Bh[bbase + f * 512];
                bfl[f] = *(short8v*)&Bl[bbase + f * 512];
            }
            #pragma unroll
            for (int fi = 0; fi < 4; ++fi)
                #pragma unroll
                for (int fj = 0; fj < 4; ++fj) {
                    acc[fi][fj] = __builtin_amdgcn_mfma_f32_16x16x32_bf16(
                        afh[fi], bfh[fj], acc[fi][fj], 0, 0, 0);
                    acc[fi][fj] = __builtin_amdgcn_mfma_f32_16x16x32_bf16(
                        afh[fi], bfl[fj], acc[fi][fj], 0, 0, 0);
                    acc[fi][fj] = __builtin_amdgcn_mfma_f32_16x16x32_bf16(
                        afl[fi], bfh[fj], acc[fi][fj], 0, 0, 0);
                }
        }
        __syncthreads();
    }

    // C/D layout: col = lane&15, row = (lane>>4)*4 + reg  [m89/m91]
    const int r = lane & 15, g = lane >> 4;
    #pragma unroll
    for (int fi = 0; fi < 4; ++fi) {
        const int gr0 = m0 + (wr << 6) + fi * 16 + g * 4;
        #pragma unroll
        for (int fj = 0; fj < 4; ++fj) {
            const int gc = n0 + (wc << 6) + fj * 16 + r;
            #pragma unroll
            for (int qq = 0; qq < 4; ++qq)
                C[(long)(gr0 + qq) * ldc + gc] = acc[fi][fj][qq] * scale;
        }
    }
}

// ---------------------------------------------------------------------------
// Fused QKV projection via split-bf16 MFMA: x[2048x512] @ {Wq|Wk|Wv}[512x512]
// -> QKV [3][BH][512][64]. Grid (12, 16).
// ---------------------------------------------------------------------------
__global__ __launch_bounds__(256)
void gemm_qkv_mfma(const float* __restrict__ x, const float* __restrict__ Wq,
                   const float* __restrict__ Wk, const float* __restrict__ Wv,
                   float* __restrict__ QKV)
{
    const int m0 = blockIdx.y << 7;
    const int ng = blockIdx.x << 7;
    const float* __restrict__ W = (ng < 512) ? Wq : (ng < 1024) ? Wk : Wv;
    const int n0 = ng & 511;
    float* __restrict__ C = QKV + (long)(ng >> 9) * (1 << 20);

    __shared__ short Ah[128 * 32], Al[128 * 32], Bh[128 * 32], Bl[128 * 32];

    const int tid = threadIdx.x;
    const int lane = tid & 63, wv = tid >> 6;
    const int wr = wv >> 1, wc = wv & 1;

    f32x4 acc[4][4] = {};

    for (int k0 = 0; k0 < 512; k0 += 32) {
        {
            const int row = tid >> 1;
            const int swz = (row & 3) ^ ((row >> 2) & 3);
            #pragma unroll
            for (int gg = 0; gg < 2; ++gg) {
                const int g = ((tid & 1) << 1) + gg;
                const float* src = x + (long)(m0 + row) * 512 + k0 + (g << 3);
                float v[8];
                *(float4*)&v[0] = *(const float4*)src;
                *(float4*)&v[4] = *(const float4*)(src + 4);
                unsigned hi[4], lo[4];
                split8(v, hi, lo);
                const int off = row * 32 + ((g ^ swz) << 3);
                *(uint4*)&Ah[off] = *(uint4*)hi;
                *(uint4*)&Al[off] = *(uint4*)lo;
            }
        }
        {
            const int n = tid & 127;
            const int swz = (n & 3) ^ ((n >> 2) & 3);
            #pragma unroll
            for (int gg = 0; gg < 2; ++gg) {
                const int g = ((tid >> 7) << 1) + gg;
                float v[8];
                #pragma unroll
                for (int e = 0; e < 8; ++e)
                    v[e] = W[(long)(k0 + (g << 3) + e) * 512 + n0 + n];
                unsigned hi[4], lo[4];
                split8(v, hi, lo);
                const int off = n * 32 + ((g ^ swz) << 3);
                *(uint4*)&Bh[off] = *(uint4*)hi;
                *(uint4*)&Bl[off] = *(uint4*)lo;
            }
        }
        __syncthreads();

        {
            const int r = lane & 15, g = lane >> 4;
            const int lswz = (r & 3) ^ ((r >> 2) & 3);
            const int gslot = ((g ^ lswz) << 3);
            const int abase = ((wr << 6) + r) * 32 + gslot;
            const int bbase = ((wc << 6) + r) * 32 + gslot;
            short8v afh[4], afl[4], bfh[4], bfl[4];
            #pragma unroll
            for (int f = 0; f < 4; ++f) {
                afh[f] = *(short8v*)&Ah[abase + f * 512];
                afl[f] = *(short8v*)&Al[abase + f * 512];
                bfh[f] = *(short8v*)&Bh[bbase + f * 512];
                bfl[f] = *(short8v*)&Bl[bbase + f * 512];
            }
            #pragma unroll
            for (int fi = 0; fi < 4; ++fi)
                #pragma unroll
                for (int fj = 0; fj < 4; ++fj) {
                    acc[fi][fj] = __builtin_amdgcn_mfma_f32_16x16x32_bf16(
                        afh[fi], bfh[fj], acc[fi][fj], 0, 0, 0);
                    acc[fi][fj] = __builtin_amdgcn_mfma_f32_16x16x32_bf16(
                        afh[fi], bfl[fj], acc[fi][fj], 0, 0, 0);
                    acc[fi][fj] = __builtin_amdgcn_mfma_f32_16x16x32_bf16(
                        afl[fi], bfh[fj], acc[fi][fj], 0, 0, 0);
                }
        }
        __syncthreads();
    }

    const int r = lane & 15, g = lane >> 4;
    #pragma unroll
    for (int fi = 0; fi < 4; ++fi) {
        const int gr0 = m0 + (wr << 6) + fi * 16 + g * 4;
        #pragma unroll
        for (int fj = 0; fj < 4; ++fj) {
            const int nl = n0 + (wc << 6) + fj * 16 + r;
            const int h = nl >> 6, d = nl & 63;
            #pragma unroll
            for (int qq = 0; qq < 4; ++qq) {
                const int m = gr0 + qq;
                const int b = m >> 9, l = m & 511;
                C[((long)((b * 8 + h) * 512 + l)) * 64 + d] = acc[fi][fj][qq];
            }
        }
    }
}

// ---------------------------------------------------------------------------
// Adjacency (R13 form): packed-fp16 asm inner loop + register prefetch +
// j-split x2 into partial buffers P0/P1 (plain coalesced stores, NO atomics).
//   Partial[i,k] = 2^-15 * sum_{j in half} u·[u > 6.4], u = S_ij*S_kj, diag 0.
// Per j-PAIR: d = pk_fma(a,b,-6.4); t = pk_max(d,0);
//   m = pk_min(pk_fma(t,32768,t), pk_add(t,6.4)); acc = pk_add(m, acc).
// Constants (f16): -6.4=0xC666, 6.4=0x4666, 32768=0x7800.
// Grid (36 upper-tri tile pairs, 2 j-halves, 32 bh). Mirror write (symmetry).
// ---------------------------------------------------------------------------
__global__ __launch_bounds__(256, 4)
void adj_kernel(const float* __restrict__ S, float* __restrict__ P0,
                float* __restrict__ P1)
{
    const int bh = blockIdx.z;
    const float* __restrict__ Sh = S + (long)bh * 262144;
    float* __restrict__ Ph = ((blockIdx.y == 0) ? P0 : P1) + (long)bh * 262144;
    const int jbase = blockIdx.y << 8;

    int ti = 0, rem = blockIdx.x;
    while (rem >= 8 - ti) { rem -= 8 - ti; ++ti; }
    const int tk = ti + rem;
    const int i0 = ti << 6, k0 = tk << 6;

    __shared__ __align__(16) char smem_raw[17408];

    const int tid  = threadIdx.x;
    const int lane = tid & 63;
    const int wv   = tid >> 6;
    const int ly8  = (lane >> 3) << 3;
    const int lx8  = (lane & 7) << 3;
    const int r4   = lane >> 2;
    const int q    = lane & 3;

    unsigned (*stgL)[68] = (unsigned(*)[68])(smem_raw + wv * 4352);
    unsigned (*stgR)[68] = (unsigned(*)[68])(smem_raw + wv * 4352 + 2176);

    const unsigned nC  = 0xC666C666u;
    const unsigned zz  = 0x00000000u;
    const unsigned big = 0x78007800u;
    const unsigned cc  = 0x46664666u;

    unsigned acc2[8][8] = {};

    const int jw = jbase + (wv << 6);
    const float* srcL = Sh + (long)(i0 + r4) * 512 + jw + (q << 2);
    const float* srcR = Sh + (long)(k0 + r4) * 512 + jw + (q << 2);

    float4 rl[4], rr[4];
    #pragma unroll
    for (int p = 0; p < 4; ++p) {
        rl[p] = *(const float4*)(srcL + (long)(p << 4) * 512);
        rr[p] = *(const float4*)(srcR + (long)(p << 4) * 512);
    }

    for (int c = 0; c < 4; ++c) {
        #pragma unroll
        for (int p = 0; p < 4; ++p) {
            const int row = r4 + (p << 4);
            h2 h0, h1;
            h0[0] = (_Float16)rl[p].x; h0[1] = (_Float16)rl[p].y;
            h1[0] = (_Float16)rl[p].z; h1[1] = (_Float16)rl[p].w;
            stgL[(q << 1) + 0][row] = __builtin_bit_cast(unsigned, h0);
            stgL[(q << 1) + 1][row] = __builtin_bit_cast(unsigned, h1);
            h0[0] = (_Float16)rr[p].x; h0[1] = (_Float16)rr[p].y;
            h1[0] = (_Float16)rr[p].z; h1[1] = (_Float16)rr[p].w;
            stgR[(q << 1) + 0][row] = __builtin_bit_cast(unsigned, h0);
            stgR[(q << 1) + 1][row] = __builtin_bit_cast(unsigned, h1);
        }
        if (c < 3) {
            const int joff = (c + 1) << 4;
            #pragma unroll
            for (int p = 0; p < 4; ++p) {
                rl[p] = *(const float4*)(srcL + (long)(p << 4) * 512 + joff);
                rr[p] = *(const float4*)(srcR + (long)(p << 4) * 512 + joff);
            }
        }
        asm volatile("s_waitcnt lgkmcnt(0)" ::: "memory");
        __builtin_amdgcn_sched_barrier(0);
        #pragma unroll
        for (int jp = 0; jp < 8; ++jp) {
            unsigned a2[8], b2[8];
            *(uint4*)&a2[0] = *(const uint4*)&stgL[jp][ly8];
            *(uint4*)&a2[4] = *(const uint4*)&stgL[jp][ly8 + 4];
            *(uint4*)&b2[0] = *(const uint4*)&stgR[jp][lx8];
            *(uint4*)&b2[4] = *(const uint4*)&stgR[jp][lx8 + 4];
            #pragma unroll
            for (int i = 0; i < 8; ++i)
                #pragma unroll
                for (int j = 0; j < 8; ++j) {
                    unsigned d, t, m1, m2, m;
                    asm("v_pk_fma_f16 %0, %1, %2, %3"
                        : "=v"(d) : "v"(a2[i]), "v"(b2[j]), "v"(nC));
                    asm("v_pk_max_f16 %0, %1, %2"
                        : "=v"(t) : "v"(d), "v"(zz));
                    asm("v_pk_fma_f16 %0, %1, %2, %3"
                        : "=v"(m1) : "v"(t), "v"(big), "v"(t));
                    asm("v_pk_add_f16 %0, %1, %2"
                        : "=v"(m2) : "v"(t), "v"(cc));
                    asm("v_pk_min_f16 %0, %1, %2"
                        : "=v"(m) : "v"(m1), "v"(m2));
                    asm("v_pk_add_f16 %0, %1, %0"
                        : "+v"(acc2[i][j]) : "v"(m));
                }
        }
    }

    // ---- quarter-wise fp32 reduce: (w0+w1)+(w3+w2) -> wave 0 ----
    float* buf0 = (float*)smem_raw;
    float* buf1 = (float*)(smem_raw + 4352);
    float  f[8][8];

    #pragma unroll
    for (int qp = 0; qp < 4; ++qp) {
        float v[16];
        #pragma unroll
        for (int e = 0; e < 16; ++e) {
            const h2 hh = __builtin_bit_cast(h2, acc2[(qp << 1) + (e >> 3)][e & 7]);
            v[e] = (float)hh[0] + (float)hh[1];
        }
        __syncthreads();
        if (wv == 1 || wv == 2) {
            float* dst = (wv == 1 ? buf0 : buf1) + lane * 17;
            #pragma unroll
            for (int e = 0; e < 16; ++e) dst[e] = v[e];
        }
        __syncthreads();
        if (wv == 0 || wv == 3) {
            const float* src = (wv == 0 ? buf0 : buf1) + lane * 17;
            #pragma unroll
            for (int e = 0; e < 16; ++e) v[e] += src[e];
        }
        __syncthreads();
        if (wv == 3) {
            float* dst = buf0 + lane * 17;
            #pragma unroll
            for (int e = 0; e < 16; ++e) dst[e] = v[e];
        }
        __syncthreads();
        if (wv == 0) {
            const float* src = buf0 + lane * 17;
            #pragma unroll
            for (int e = 0; e < 16; ++e)
                f[(qp << 1) + (e >> 3)][e & 7] = v[e] + src[e];
        }
    }

    if (wv == 0) {
        const float SC = 1.0f / 32768.0f;    // 2^-15 = (1/64)*(1/512), exact
        #pragma unroll
        for (int i = 0; i < 8; ++i)
            #pragma unroll
            for (int j = 0; j < 8; ++j)
                f[i][j] *= SC;
        if (ti == tk) {
            #pragma unroll
            for (int i = 0; i < 8; ++i)
                #pragma unroll
                for (int j = 0; j < 8; ++j)
                    if (ly8 + i == lx8 + j) f[i][j] = 0.0f;
        }
        #pragma unroll
        for (int i = 0; i < 8; ++i) {
            float* dst = Ph + (long)(i0 + ly8 + i) * 512 + k0 + lx8;
            *(float4*)dst       = make_float4(f[i][0], f[i][1], f[i][2], f[i][3]);
            *(float4*)(dst + 4) = make_float4(f[i][4], f[i][5], f[i][6], f[i][7]);
        }
        if (ti != tk) {
            #pragma unroll
            for (int j = 0; j < 8; ++j) {
                float* dst = Ph + (long)(k0 + lx8 + j) * 512 + i0 + ly8;
                *(float4*)dst       = make_float4(f[0][j], f[1][j], f[2][j], f[3][j]);
                *(float4*)(dst + 4) = make_float4(f[4][j], f[5][j], f[6][j], f[7][j]);
            }
        }
    }
}

// ---------------------------------------------------------------------------
// Row degree from partials: R[row] = 1/sqrt(clip(1 + sum(P0+P1), 1e-6))
// ---------------------------------------------------------------------------
__global__ __launch_bounds__(256)
void rowsum_kernel(const float* __restrict__ P0, const float* __restrict__ P1,
                   float* __restrict__ R)
{
    const int row = (blockIdx.x << 2) + (threadIdx.x >> 6);
    const int lane = threadIdx.x & 63;
    const float* p0 = P0 + (long)row * 512;
    const float* p1 = P1 + (long)row * 512;
    float s = 0.0f;
    #pragma unroll
    for (int t = 0; t < 8; ++t) s += p0[lane + (t << 6)] + p1[lane + (t << 6)];
    #pragma unroll
    for (int off = 32; off; off >>= 1) s += __shfl_xor(s, off, 64);
    if (lane == 0) R[row] = 1.0f / sqrtf(fmaxf(1.0f + s, 1e-6f));
}

// ---------------------------------------------------------------------------
// A_hat[i,k] = R[i]*R[k]*((P0+P1) + (i==k)) -> written to P0
// ---------------------------------------------------------------------------
__global__ __launch_bounds__(256)
void ahat_kernel(float* __restrict__ P0, const float* __restrict__ P1,
                 const float* __restrict__ R)
{
    const long i4 = ((long)blockIdx.x * 256 + threadIdx.x) << 2;
    const long off = i4 & 262143;
    const long bh = i4 >> 18;
    const int i = (int)(off >> 9);
    const int k = (int)(off & 511);
    const float ri = R[(bh << 9) + i];
    const float* Rk = R + (bh << 9) + k;
    float4 v0 = *(float4*)(P0 + i4);
    float4 v1 = *(const float4*)(P1 + i4);
    v0.x = ri * Rk[0] * ((v0.x + v1.x) + ((k + 0) == i ? 1.0f : 0.0f));
    v0.y = ri * Rk[1] * ((v0.y + v1.y) + ((k + 1) == i ? 1.0f : 0.0f));
    v0.z = ri * Rk[2] * ((v0.z + v1.z) + ((k + 2) == i ? 1.0f : 0.0f));
    v0.w = ri * Rk[3] * ((v0.w + v1.w) + ((k + 3) == i ? 1.0f : 0.0f));
    *(float4*)(P0 + i4) = v0;
}

// ---------------------------------------------------------------------------
// Row max + inverse exp-sum of J. Wave per row, 4 rows/block.
// Identical reduce order to the old softmax kernel (bit-identical values).
// ---------------------------------------------------------------------------
__global__ __launch_bounds__(256)
void rowmaxsum_kernel(const float* __restrict__ J, float* __restrict__ MX,
                      float* __restrict__ INV)
{
    const int row = (blockIdx.x << 2) + (threadIdx.x >> 6);
    const int lane = threadIdx.x & 63;
    const float* p = J + (long)row * 512 + (lane << 3);
    float4 v0 = *(const float4*)p;
    float4 v1 = *(const float4*)(p + 4);
    float mx = fmaxf(fmaxf(fmaxf(v0.x, v0.y), fmaxf(v0.z, v0.w)),
                     fmaxf(fmaxf(v1.x, v1.y), fmaxf(v1.z, v1.w)));
    #pragma unroll
    for (int off = 32; off; off >>= 1) mx = fmaxf(mx, __shfl_xor(mx, off, 64));
    float e[8];
    e[0] = __expf(v0.x - mx); e[1] = __expf(v0.y - mx);
    e[2] = __expf(v0.z - mx); e[3] = __expf(v0.w - mx);
    e[4] = __expf(v1.x - mx); e[5] = __expf(v1.y - mx);
    e[6] = __expf(v1.z - mx); e[7] = __expf(v1.w - mx);
    float s = (((e[0] + e[1]) + (e[2] + e[3])) + ((e[4] + e[5]) + (e[6] + e[7])));
    #pragma unroll
    for (int off = 32; off; off >>= 1) s += __shfl_xor(s, off, 64);
    if (lane == 0) { MX[row] = mx; INV[row] = 1.0f / s; }
}

// ---------------------------------------------------------------------------
// O = softmax(J) @ V per head via split-bf16 MFMA; softmax applied in staging
// (p = expf(J - MX[row]) * INV[row], identical arithmetic to the old
// standalone softmax). Writes DIRECTLY to Of [B][L][H*HD].
// 128x64 tile, 4 waves stacked on M. Grid (1, 4, 32).
// ---------------------------------------------------------------------------
__global__ __launch_bounds__(256)
void gemm_pv_mfma(const float* __restrict__ J, const float* __restrict__ V,
                  const float* __restrict__ MX, const float* __restrict__ INV,
                  float* __restrict__ Of)
{
    const int bh = blockIdx.z;
    const float* __restrict__ Pp = J + (long)bh * 262144;
    const float* __restrict__ Vp = V + (long)bh * 32768;
    const float* __restrict__ MXb = MX + ((long)bh << 9);
    const float* __restrict__ INVb = INV + ((long)bh << 9);
    const int bb = bh >> 3, hh = bh & 7;
    const int m0 = blockIdx.y << 7;

    __shared__ short Ph[128 * 32], Pl[128 * 32], Vh[64 * 32], Vl[64 * 32];

    const int tid = threadIdx.x;
    const int lane = tid & 63, wv = tid >> 6;

    f32x4 acc[2][4] = {};

    for (int k0 = 0; k0 < 512; k0 += 32) {
        {
            const int row = tid >> 1;
            const float mx = MXb[m0 + row], inv = INVb[m0 + row];
            const int swz = (row & 3) ^ ((row >> 2) & 3);
            #pragma unroll
            for (int gg = 0; gg < 2; ++gg) {
                const int g = ((tid & 1) << 1) + gg;
                const float* src = Pp + (long)(m0 + row) * 512 + k0 + (g << 3);
                float v[8];
                *(float4*)&v[0] = *(const float4*)src;
                *(float4*)&v[4] = *(const float4*)(src + 4);
                #pragma unroll
                for (int e = 0; e < 8; ++e)
                    v[e] = __expf(v[e] - mx) * inv;
                unsigned hi[4], lo[4];
                split8(v, hi, lo);
                const int off = row * 32 + ((g ^ swz) << 3);
                *(uint4*)&Ph[off] = *(uint4*)hi;
                *(uint4*)&Pl[off] = *(uint4*)lo;
            }
        }
        {
            const int n = tid & 63, g = tid >> 6;
            const int swz = (n & 3) ^ ((n >> 2) & 3);
            float v[8];
            #pragma unroll
            for (int e = 0; e < 8; ++e)
                v[e] = Vp[(long)(k0 + (g << 3) + e) * 64 + n];
            unsigned hi[4], lo[4];
            split8(v, hi, lo);
            const int off = n * 32 + ((g ^ swz) << 3);
            *(uint4*)&Vh[off] = *(uint4*)hi;
            *(uint4*)&Vl[off] = *(uint4*)lo;
        }
        __syncthreads();

        {
            const int r = lane & 15, g = lane >> 4;
            const int lswz = (r & 3) ^ ((r >> 2) & 3);
            const int gslot = ((g ^ lswz) << 3);
            short8v afh[2], afl[2], bfh[4], bfl[4];
            #pragma unroll
            for (int fi = 0; fi < 2; ++fi) {
                const int abase = ((wv << 5) + (fi << 4) + r) * 32 + gslot;
                afh[fi] = *(short8v*)&Ph[abase];
                afl[fi] = *(short8v*)&Pl[abase];
            }
            #pragma unroll
            for (int fj = 0; fj < 4; ++fj) {
                const int bbase = ((fj << 4) + r) * 32 + gslot;
                bfh[fj] = *(short8v*)&Vh[bbase];
                bfl[fj] = *(short8v*)&Vl[bbase];
            }
            #pragma unroll
            for (int fi = 0; fi < 2; ++fi)
                #pragma unroll
                for (int fj = 0; fj < 4; ++fj) {
                    acc[fi][fj] = __builtin_amdgcn_mfma_f32_16x16x32_bf16(
                        afh[fi], bfh[fj], acc[fi][fj], 0, 0, 0);
                    acc[fi][fj] = __builtin_amdgcn_mfma_f32_16x16x32_bf16(
                        afh[fi], bfl[fj], acc[fi][fj], 0, 0, 0);
                    acc[fi][fj] = __builtin_amdgcn_mfma_f32_16x16x32_bf16(
                        afl[fi], bfh[fj], acc[fi][fj], 0, 0, 0);
                }
        }
        __syncthreads();
    }

    const int r = lane & 15, g = lane >> 4;
    #pragma unroll
    for (int fi = 0; fi < 2; ++fi) {
        const int l0 = m0 + (wv << 5) + fi * 16 + g * 4;
        #pragma unroll
        for (int fj = 0; fj < 4; ++fj) {
            const int d = fj * 16 + r;
            #pragma unroll
            for (int qq = 0; qq < 4; ++qq)
                Of[((long)((bb << 9) + l0 + qq) << 9) + (hh << 6) + d] = acc[fi][fj][qq];
        }
    }
}

// ---------------------------------------------------------------------------
extern "C" void kernel_launch(void* const* d_in, const int* in_sizes, int n_in,
                              void* d_out, int out_size, void* d_ws, size_t ws_size,
                              hipStream_t stream)
{
    const float* x  = (const float*)d_in[0];
    const float* Wq = (const float*)d_in[1];
    const float* Wk = (const float*)d_in[2];
    const float* Wv = (const float*)d_in[3];
    const float* Wo = (const float*)d_in[4];
    float* out = (float*)d_out;

    float* ws = (float*)d_ws;
    float* Q  = ws;                       // 1M floats (QKV base; later Of)
    float* Kt = Q  + (1u << 20);          // 1M
    float* V  = Kt + (1u << 20);          // 1M
    float* S  = V  + (1u << 20);          // 8M
    float* Am = S  + (8u << 20);          // 8M (adj partial 0 -> A_hat)
    float* T  = Am + (8u << 20);          // 8M (adj partial 1 -> A_hat@S temp)
    float* R  = T  + (8u << 20);          // 16K
    float* MX = R  + 16384;               // 16K
    float* INV = MX + 16384;              // 16K

    dim3 blk(256);

    // 1) fused QKV projections (split-bf16 MFMA)
    gemm_qkv_mfma<<<dim3(12, 16, 1), blk, 0, stream>>>(x, Wq, Wk, Wv, Q);

    // 2) S = Q K^T per head (MFMA, K=64)
    gemm_mfma<1><<<dim3(4, 4, 32), blk, 0, stream>>>(Q, Kt, S, 64, 64, 64, 512,
                                                     32768, 32768, 262144, 1.0f);

    // 3) adjacency partials (packed-fp16 asm, prefetch, j-split x2)
    adj_kernel<<<dim3(36, 2, 32), blk, 0, stream>>>(S, Am, T);

    // 4) row degrees -> R (combines partials)
    rowsum_kernel<<<dim3(4096), blk, 0, stream>>>(Am, T, R);

    // 5) A_hat (combines partials) -> Am
    ahat_kernel<<<dim3(8192), blk, 0, stream>>>(Am, T, R);

    // 6) T = A_hat @ S (MFMA, 128x128)
    gemm_mfma<0><<<dim3(4, 4, 32), blk, 0, stream>>>(Am, S, T, 512, 512, 512, 512,
                                                     262144, 262144, 262144, 1.0f);

    // 7) J = T @ A_hat^T / 8 -> S (MFMA, 128x128)
    gemm_mfma<1><<<dim3(4, 4, 32), blk, 0, stream>>>(T, Am, S, 512, 512, 512, 512,
                                                     262144, 262144, 262144, 0.125f);

    // 8) row max + inv exp-sum of J (replaces in-place softmax round trip)
    rowmaxsum_kernel<<<dim3(4096), blk, 0, stream>>>(S, MX, INV);

    // 9) O = softmax(J) @ V -> Of directly (softmax in staging; reuse Q)
    gemm_pv_mfma<<<dim3(1, 4, 32), blk, 0, stream>>>(S, V, MX, INV, Q);

    // 10) out = Of @ Wo (MFMA, 128x128)
    gemm_mfma<0><<<dim3(4, 16, 1), blk, 0, stream>>>(Q, Wo, out, 512, 512, 512, 512,
                                                     0, 0, 0, 1.0f);
}